// Round 3
// baseline (1543.178 us; speedup 1.0000x reference)
//
#include <hip/hip_runtime.h>

#define T_SEQ 2048
#define HID   5120
#define QLR   1536
#define KVLR  512
#define NOPE  128
#define ROPE_D 64
#define VDIM  128
#define NH    32
#define QKD   192

constexpr float SCALE   = 0.07216878364870323f; // 192^-0.5
constexpr float EPS_F   = 1e-6f;
constexpr float LN10000 = 9.210340371976184f;

typedef __bf16 bf16x8 __attribute__((ext_vector_type(8)));
typedef float  f32x4  __attribute__((ext_vector_type(4)));

__device__ __forceinline__ unsigned short f2bf(float f) {
  union { float f; unsigned u; } v; v.f = f;
  unsigned u = v.u + 0x7fffu + ((v.u >> 16) & 1u);
  return (unsigned short)(u >> 16);
}
__device__ __forceinline__ float bf2f(unsigned short b) {
  union { unsigned u; float f; } v; v.u = ((unsigned)b) << 16;
  return v.f;
}

// async global->LDS, 16B per lane; LDS dest = wave-uniform base + lane*16
__device__ __forceinline__ void glds16(const unsigned short* g, unsigned short* l) {
  __builtin_amdgcn_global_load_lds((const __attribute__((address_space(1))) void*)g,
                                   (__attribute__((address_space(3))) void*)l, 16, 0, 0);
}

// Frag-contiguous layouts (16x16x32 bf16 MFMA B-operand):
//   B-frag lane = (n & 15) | (((k >> 3) & 3) << 4), elem = k & 7  (16B/lane, 1 KB/frag)
// k_frag[key-group kg = key>>4][dim-step ds = dim>>5][512 elems]   (kg: 128, ds: 18)
// v_frag[vd-group vg = vd>>4][key-step ks = key>>5][512 elems]     (vg: 32, ks: 64)
__device__ __forceinline__ long kfrag_off(int key, int dim) {
  return ((long)(key >> 4) * 18 + (dim >> 5)) * 512 +
         ((key & 15) + 16 * ((dim >> 3) & 3)) * 8 + (dim & 7);
}
__device__ __forceinline__ long vfrag_off(int vd, int key) {
  return ((long)(vd >> 4) * 64 + (key >> 5)) * 512 +
         ((vd & 15) + 16 * ((key >> 3) & 3)) * 8 + (key & 7);
}

// ---------------- elementwise f32 -> bf16 ----------------
__global__ void conv_f2b(const float* __restrict__ in, unsigned short* __restrict__ out, long n) {
  long i = ((long)blockIdx.x * blockDim.x + threadIdx.x) * 4;
  if (i >= n) return;
  float4 v = *(const float4*)(in + i);
  uint2 o;
  o.x = (unsigned)f2bf(v.x) | ((unsigned)f2bf(v.y) << 16);
  o.y = (unsigned)f2bf(v.z) | ((unsigned)f2bf(v.w) << 16);
  *(uint2*)(out + i) = o;
}

// ---------------- transpose f32 (RxC) -> bf16 (CxR), batched ----------------
__global__ void transpose_f2b(const float* __restrict__ in, unsigned short* __restrict__ out,
                              int R, int C, long inB, long outB) {
  __shared__ float tile[32][33];
  const float* inp = in + (long)blockIdx.z * inB;
  unsigned short* outp = out + (long)blockIdx.z * outB;
  int c0 = blockIdx.x * 32, r0 = blockIdx.y * 32;
  int x = threadIdx.x, y = threadIdx.y; // (32,8)
#pragma unroll
  for (int yy = 0; yy < 32; yy += 8)
    tile[y + yy][x] = inp[(long)(r0 + y + yy) * C + c0 + x];
  __syncthreads();
#pragma unroll
  for (int yy = 0; yy < 32; yy += 8)
    outp[(long)(c0 + y + yy) * R + r0 + x] = f2bf(tile[x][y + yy]);
}

// ---------------- rmsnorm rows (f32 in, bf16 out) ----------------
__global__ void rmsnorm_rows(const float* __restrict__ in, const float* __restrict__ w,
                             unsigned short* __restrict__ out, int C) {
  int t = blockIdx.x, tid = threadIdx.x;
  __shared__ float sred[4];
  const float* row = in + (long)t * C;
  float ss = 0.f;
  for (int i = tid; i < C; i += 256) { float v = row[i]; ss += v * v; }
#pragma unroll
  for (int o = 32; o; o >>= 1) ss += __shfl_xor(ss, o);
  if ((tid & 63) == 0) sred[tid >> 6] = ss;
  __syncthreads();
  ss = sred[0] + sred[1] + sred[2] + sred[3];
  float rinv = rsqrtf(ss / (float)C + EPS_F);
  for (int i = tid; i < C; i += 256)
    out[(long)t * C + i] = f2bf(row[i] * rinv * w[i]);
}

// ---------------- kv latent: rmsnorm(512) -> k_frag & v_frag; rope -> k_frag ----------------
__global__ void norm_rope_k(const float* __restrict__ latent, const float* __restrict__ w,
                            unsigned short* __restrict__ k_frag, unsigned short* __restrict__ v_frag) {
  int t = blockIdx.x, tid = threadIdx.x;
  __shared__ float sred[4];
  const float* row = latent + (long)t * 576;
  float ss = 0.f;
  for (int i = tid; i < 512; i += 256) { float v = row[i]; ss += v * v; }
#pragma unroll
  for (int o = 32; o; o >>= 1) ss += __shfl_xor(ss, o);
  if ((tid & 63) == 0) sred[tid >> 6] = ss;
  __syncthreads();
  ss = sred[0] + sred[1] + sred[2] + sred[3];
  float rinv = rsqrtf(ss * (1.f / 512.f) + EPS_F);
  for (int i = tid; i < 512; i += 256) {
    unsigned short b = f2bf(row[i] * rinv * w[i]);
    k_frag[kfrag_off(t, i)] = b;  // key = t, dim = i
    v_frag[vfrag_off(i, t)] = b;  // vd = i, key = t
  }
  if (tid < 32) {
    float fr = (float)t * expf(-((float)(2 * tid) / 64.f) * LN10000);
    float c = cosf(fr), s = sinf(fr);
    float x1 = row[512 + 2 * tid], x2 = row[512 + 2 * tid + 1];
    int d0 = 512 + 2 * tid;
    k_frag[kfrag_off(t, d0)]     = f2bf(x1 * c - x2 * s);
    k_frag[kfrag_off(t, d0 + 1)] = f2bf(x2 * c + x1 * s);
  }
}

// ---------------- rope on q_pe: q (T, H*192) -> q_input[h][t][512..576] ----------------
__global__ void rope_q(const unsigned short* __restrict__ q, unsigned short* __restrict__ q_input) {
  int idx = blockIdx.x * 256 + threadIdx.x; // t*NH*32 + h*32 + i
  int i = idx & 31, h = (idx >> 5) & 31, t = idx >> 10;
  float fr = (float)t * expf(-((float)(2 * i) / 64.f) * LN10000);
  float c = cosf(fr), s = sinf(fr);
  const unsigned short* qp = q + (long)t * (NH * QKD) + h * QKD + NOPE + 2 * i;
  float x1 = bf2f(qp[0]), x2 = bf2f(qp[1]);
  unsigned short* op = q_input + ((long)h * T_SEQ + t) * 576 + 512 + 2 * i;
  op[0] = f2bf(x1 * c - x2 * s);
  op[1] = f2bf(x2 * c + x1 * s);
}

// ---------------- GEMM: C[M,N] = A[M,K] @ Bt[N,K]^T (bf16 in, f32 acc) ----------------
template <bool OUT_BF16>
__global__ __launch_bounds__(256, 2)
void gemm_bt(const unsigned short* __restrict__ A, const unsigned short* __restrict__ Bt,
             void* __restrict__ Cv, int N, int K,
             long lda, long ldb, long ldc, long bA, long bB, long bC) {
  __shared__ __align__(16) unsigned short sA[128 * 64];
  __shared__ __align__(16) unsigned short sB[128 * 64];
  const int b = blockIdx.z;
  const unsigned short* Ap = A + (long)b * bA;
  const unsigned short* Bp = Bt + (long)b * bB;
  const int m0 = blockIdx.x * 128, n0 = blockIdx.y * 128;
  const int tid = threadIdx.x, lane = tid & 63, w = tid >> 6;
  const int wr = w >> 1, wc = w & 1, lo = lane & 15, hi = lane >> 4;
  f32x4 acc[4][4];
#pragma unroll
  for (int i = 0; i < 4; i++)
#pragma unroll
    for (int j = 0; j < 4; j++) acc[i][j] = (f32x4){0.f, 0.f, 0.f, 0.f};
  const int r0 = tid >> 3, cc = tid & 7;
  for (int k0 = 0; k0 < K; k0 += 64) {
    __syncthreads();
#pragma unroll
    for (int i = 0; i < 4; i++) {
      glds16(Ap + (long)(m0 + i * 32 + r0) * lda + k0 + cc * 8, sA + i * 2048 + w * 512);
      glds16(Bp + (long)(n0 + i * 32 + r0) * ldb + k0 + cc * 8, sB + i * 2048 + w * 512);
    }
    __syncthreads();
#pragma unroll
    for (int s = 0; s < 2; s++) {
      bf16x8 af[4], bfr[4];
#pragma unroll
      for (int mt = 0; mt < 4; mt++)
        af[mt] = *(const bf16x8*)(sA + (wr * 64 + mt * 16 + lo) * 64 + s * 32 + hi * 8);
#pragma unroll
      for (int nt = 0; nt < 4; nt++)
        bfr[nt] = *(const bf16x8*)(sB + (wc * 64 + nt * 16 + lo) * 64 + s * 32 + hi * 8);
#pragma unroll
      for (int mt = 0; mt < 4; mt++)
#pragma unroll
        for (int nt = 0; nt < 4; nt++)
          acc[mt][nt] = __builtin_amdgcn_mfma_f32_16x16x32_bf16(af[mt], bfr[nt], acc[mt][nt], 0, 0, 0);
    }
  }
#pragma unroll
  for (int mt = 0; mt < 4; mt++)
#pragma unroll
    for (int nt = 0; nt < 4; nt++) {
      int col = n0 + wc * 64 + nt * 16 + lo;
      if (col < N) {
#pragma unroll
        for (int r = 0; r < 4; r++) {
          long row = m0 + wr * 64 + mt * 16 + hi * 4 + r;
          float v = acc[mt][nt][r];
          if constexpr (OUT_BF16)
            ((unsigned short*)Cv)[(long)b * bC + row * ldc + col] = f2bf(v);
          else
            ((float*)Cv)[(long)b * bC + row * ldc + col] = v;
        }
      }
    }
}

// ---------------- flash attention v3: BARRIER-FREE ----------------
// grid (NH, T/64), i-tiles reversed. 4 waves, 16 Q-rows/wave, Q in regs.
// K and V MFMA B-frags read DIRECTLY from global in frag-contiguous layout
// (1 KB fully-coalesced load per frag, L2-resident buffers). Only LDS use is
// the wave-private P round-trip -> zero __syncthreads in the j-loop.
#define PK 72
__global__ __launch_bounds__(256, 2)
void flash_attn(const unsigned short* __restrict__ q_input,
                const unsigned short* __restrict__ k_frag,
                const unsigned short* __restrict__ v_frag,
                unsigned short* __restrict__ ctx_out) {
  __shared__ __align__(16) unsigned short sP[4][16 * PK];  // 18.4 KB, wave-private slabs
  const int h = blockIdx.x;
  const int i0 = (gridDim.y - 1 - blockIdx.y) * 64;  // biggest blocks dispatch first
  const int tid = threadIdx.x;
  const int lane = tid & 63, w = tid >> 6;
  const int lo = lane & 15, hi = lane >> 4;

  bf16x8 qf[18];
  {
    const unsigned short* qrow = q_input + ((long)h * T_SEQ + i0 + w * 16 + lo) * 576;
#pragma unroll
    for (int i = 0; i < 18; i++) qf[i] = *(const bf16x8*)(qrow + i * 32 + hi * 8);
  }
  float m_r[4], l_r[4];
#pragma unroll
  for (int r = 0; r < 4; r++) { m_r[r] = -1e30f; l_r[r] = 0.f; }
  f32x4 of[32];
#pragma unroll
  for (int o = 0; o < 32; o++) of[o] = (f32x4){0.f, 0.f, 0.f, 0.f};

  unsigned short* sp = sP[w];  // wave-private: lgkmcnt ordering only, no barriers

  for (int j0 = 0; j0 <= i0; j0 += 64) {
    // ---------- phase A: S = Q K^T, B-frags straight from k_frag ----------
    f32x4 sacc[4];
    const unsigned short* kf = k_frag + (long)(j0 >> 4) * 18 * 512 + lane * 8;
#pragma unroll
    for (int nt = 0; nt < 4; nt++) {
      const unsigned short* kfn = kf + (long)nt * 18 * 512;
      f32x4 a = (f32x4){0.f, 0.f, 0.f, 0.f};
#pragma unroll
      for (int ds = 0; ds < 18; ds++) {
        bf16x8 bb = *(const bf16x8*)(kfn + ds * 512);
        a = __builtin_amdgcn_mfma_f32_16x16x32_bf16(qf[ds], bb, a, 0, 0, 0);
      }
      sacc[nt] = a;
    }
    // ---------- phase B: online softmax ----------
    const bool diag = (j0 == i0);
    float alpha[4];
#pragma unroll
    for (int r = 0; r < 4; r++) {
      int row = i0 + w * 16 + hi * 4 + r;
      float mx = -1e30f;
#pragma unroll
      for (int nt = 0; nt < 4; nt++) {
        float v = sacc[nt][r] * SCALE;
        if (diag && (j0 + nt * 16 + lo) > row) v = -1e30f;
        sacc[nt][r] = v;
        mx = fmaxf(mx, v);
      }
#pragma unroll
      for (int o = 1; o < 16; o <<= 1) mx = fmaxf(mx, __shfl_xor(mx, o));
      float mn = fmaxf(m_r[r], mx);
      alpha[r] = __expf(m_r[r] - mn);
      m_r[r] = mn;
      float ps = 0.f;
#pragma unroll
      for (int nt = 0; nt < 4; nt++) {
        float pv = __expf(sacc[nt][r] - mn);
        sacc[nt][r] = pv;
        ps += pv;
      }
#pragma unroll
      for (int o = 1; o < 16; o <<= 1) ps += __shfl_xor(ps, o);
      l_r[r] = l_r[r] * alpha[r] + ps;
    }
#pragma unroll
    for (int o = 0; o < 32; o++)
#pragma unroll
      for (int r = 0; r < 4; r++) of[o][r] *= alpha[r];
#pragma unroll
    for (int nt = 0; nt < 4; nt++)
#pragma unroll
      for (int r = 0; r < 4; r++)
        sp[(hi * 4 + r) * PK + nt * 16 + lo] = f2bf(sacc[nt][r]);
    // ---------- phase C: O += P V, B-frags straight from v_frag ----------
    {
      const unsigned short* vf = v_frag + (long)(j0 >> 5) * 512 + lane * 8;
      bf16x8 a0 = *(const bf16x8*)(sp + lo * PK + hi * 8);
      bf16x8 a1 = *(const bf16x8*)(sp + lo * PK + 32 + hi * 8);
#pragma unroll
      for (int o = 0; o < 32; o++) {
        const unsigned short* vfo = vf + (long)o * 64 * 512;
        bf16x8 b0 = *(const bf16x8*)(vfo);
        bf16x8 b1 = *(const bf16x8*)(vfo + 512);
        of[o] = __builtin_amdgcn_mfma_f32_16x16x32_bf16(a0, b0, of[o], 0, 0, 0);
        of[o] = __builtin_amdgcn_mfma_f32_16x16x32_bf16(a1, b1, of[o], 0, 0, 0);
      }
    }
  }
  float inv_l[4];
#pragma unroll
  for (int r = 0; r < 4; r++) inv_l[r] = 1.f / l_r[r];
#pragma unroll
  for (int o = 0; o < 32; o++)
#pragma unroll
    for (int r = 0; r < 4; r++) {
      long row = (long)h * T_SEQ + i0 + w * 16 + hi * 4 + r;
      ctx_out[row * 576 + o * 16 + lo] = f2bf(of[o][r] * inv_l[r]);
    }
}

// ---------------- host orchestration ----------------
extern "C" void kernel_launch(void* const* d_in, const int* in_sizes, int n_in,
                              void* d_out, int out_size, void* d_ws, size_t ws_size,
                              hipStream_t stream) {
  (void)in_sizes; (void)n_in; (void)out_size; (void)ws_size;
  const float* hs    = (const float*)d_in[0];
  const float* wqa   = (const float*)d_in[2];
  const float* qlnw  = (const float*)d_in[3];
  const float* wqb   = (const float*)d_in[4];
  const float* wkva  = (const float*)d_in[5];
  const float* kvlnw = (const float*)d_in[6];
  const float* wkc   = (const float*)d_in[7];
  const float* wvc   = (const float*)d_in[8];
  const float* wo    = (const float*)d_in[9];
  float* out = (float*)d_out;

  char* base = (char*)d_ws;
  size_t off = 0;
  auto alloc = [&](size_t bytes) {
    char* r = base + off;
    off += (bytes + 255) & ~(size_t)255;
    return r;
  };
  unsigned short* hs_b  = (unsigned short*)alloc((size_t)T_SEQ * HID * 2);
  unsigned short* wqaT  = (unsigned short*)alloc((size_t)QLR * HID * 2);
  unsigned short* wqbT  = (unsigned short*)alloc((size_t)NH * QKD * QLR * 2);
  unsigned short* wkvaT = (unsigned short*)alloc((size_t)640 * HID * 2);  // 576 padded to 640
  unsigned short* wkcT  = (unsigned short*)alloc((size_t)NH * 512 * 128 * 2);
  unsigned short* wvcT  = (unsigned short*)alloc((size_t)NH * 128 * 512 * 2);
  float*          q_a   = (float*)alloc((size_t)T_SEQ * QLR * 4);
  unsigned short* q_a_n = (unsigned short*)alloc((size_t)T_SEQ * QLR * 2);
  unsigned short* qbuf  = (unsigned short*)alloc((size_t)T_SEQ * NH * QKD * 2);
  float*          latent= (float*)alloc((size_t)T_SEQ * 576 * 4);
  unsigned short* k_frag= (unsigned short*)alloc((size_t)128 * 18 * 512 * 2);  // 2.25 MB
  unsigned short* v_frag= (unsigned short*)alloc((size_t)32 * 64 * 512 * 2);   // 2.0 MB
  unsigned short* q_inp = (unsigned short*)alloc((size_t)NH * T_SEQ * 576 * 2);
  unsigned short* woT   = (unsigned short*)base;  // over hs_b+wqaT+wqbT (dead by then)
  unsigned short* attn  = qbuf;                   // over qbuf (dead by then)

  dim3 tb(32, 8);
  conv_f2b<<<(T_SEQ * HID) / 1024, 256, 0, stream>>>(hs, hs_b, (long)T_SEQ * HID);
  transpose_f2b<<<dim3(QLR / 32, HID / 32, 1), tb, 0, stream>>>(wqa, wqaT, HID, QLR, 0, 0);
  transpose_f2b<<<dim3(576 / 32, HID / 32, 1), tb, 0, stream>>>(wkva, wkvaT, HID, 576, 0, 0);
  gemm_bt<false><<<dim3(T_SEQ / 128, QLR / 128, 1), 256, 0, stream>>>(
      hs_b, wqaT, q_a, QLR, HID, HID, HID, QLR, 0, 0, 0);
  gemm_bt<false><<<dim3(T_SEQ / 128, 5, 1), 256, 0, stream>>>(
      hs_b, wkvaT, latent, 576, HID, HID, HID, 576, 0, 0, 0);
  rmsnorm_rows<<<T_SEQ, 256, 0, stream>>>(q_a, qlnw, q_a_n, QLR);
  norm_rope_k<<<T_SEQ, 256, 0, stream>>>(latent, kvlnw, k_frag, v_frag);
  transpose_f2b<<<dim3((NH * QKD) / 32, QLR / 32, 1), tb, 0, stream>>>(wqb, wqbT, QLR, NH * QKD, 0, 0);
  gemm_bt<true><<<dim3(T_SEQ / 128, (NH * QKD) / 128, 1), 256, 0, stream>>>(
      q_a_n, wqbT, qbuf, NH * QKD, QLR, QLR, QLR, NH * QKD, 0, 0, 0);
  transpose_f2b<<<dim3(512 / 32, 128 / 32, NH), tb, 0, stream>>>(wkc, wkcT, 128, 512, 65536, 65536);
  gemm_bt<true><<<dim3(T_SEQ / 128, 512 / 128, NH), 256, 0, stream>>>(
      qbuf, wkcT, q_inp, 512, 128, NH * QKD, 128, 576, QKD, 65536, (long)T_SEQ * 576);
  rope_q<<<(T_SEQ * NH * 32) / 256, 256, 0, stream>>>(qbuf, q_inp);
  flash_attn<<<dim3(NH, T_SEQ / 64), 256, 0, stream>>>(q_inp, k_frag, v_frag, q_inp);
  transpose_f2b<<<dim3(128 / 32, 512 / 32, NH), tb, 0, stream>>>(wvc, wvcT, 512, 128, 65536, 65536);
  gemm_bt<true><<<dim3(T_SEQ / 128, 1, NH), 256, 0, stream>>>(
      q_inp, wvcT, attn, 128, 512, 576, 512, NH * VDIM, (long)T_SEQ * 576, 65536, 128);
  transpose_f2b<<<dim3(HID / 32, (NH * VDIM) / 32, 1), tb, 0, stream>>>(wo, woT, NH * VDIM, HID, 0, 0);
  gemm_bt<false><<<dim3(T_SEQ / 128, HID / 128, 1), 256, 0, stream>>>(
      attn, woT, out, HID, NH * VDIM, NH * VDIM, NH * VDIM, HID, 0, 0, 0);
}

// Round 4
// 1074.454 us; speedup vs baseline: 1.4362x; 1.4362x over previous
//
#include <hip/hip_runtime.h>

#define T_SEQ 2048
#define HID   5120
#define QLR   1536
#define KVLR  512
#define NOPE  128
#define ROPE_D 64
#define VDIM  128
#define NH    32
#define QKD   192

constexpr float SCALE   = 0.07216878364870323f; // 192^-0.5
constexpr float EPS_F   = 1e-6f;
constexpr float LN10000 = 9.210340371976184f;

typedef __bf16 bf16x8 __attribute__((ext_vector_type(8)));
typedef float  f32x4  __attribute__((ext_vector_type(4)));

__device__ __forceinline__ unsigned short f2bf(float f) {
  union { float f; unsigned u; } v; v.f = f;
  unsigned u = v.u + 0x7fffu + ((v.u >> 16) & 1u);
  return (unsigned short)(u >> 16);
}
__device__ __forceinline__ float bf2f(unsigned short b) {
  union { unsigned u; float f; } v; v.u = ((unsigned)b) << 16;
  return v.f;
}

// async global->LDS, 16B per lane; LDS dest = wave-uniform base + lane*16
__device__ __forceinline__ void glds16(const unsigned short* g, unsigned short* l) {
  __builtin_amdgcn_global_load_lds((const __attribute__((address_space(1))) void*)g,
                                   (__attribute__((address_space(3))) void*)l, 16, 0, 0);
}

// ---------------- elementwise f32 -> bf16 ----------------
__global__ void conv_f2b(const float* __restrict__ in, unsigned short* __restrict__ out, long n) {
  long i = ((long)blockIdx.x * blockDim.x + threadIdx.x) * 4;
  if (i >= n) return;
  float4 v = *(const float4*)(in + i);
  uint2 o;
  o.x = (unsigned)f2bf(v.x) | ((unsigned)f2bf(v.y) << 16);
  o.y = (unsigned)f2bf(v.z) | ((unsigned)f2bf(v.w) << 16);
  *(uint2*)(out + i) = o;
}

// ---------------- transpose f32 (RxC) -> bf16 (CxR), batched ----------------
__global__ void transpose_f2b(const float* __restrict__ in, unsigned short* __restrict__ out,
                              int R, int C, long inB, long outB) {
  __shared__ float tile[32][33];
  const float* inp = in + (long)blockIdx.z * inB;
  unsigned short* outp = out + (long)blockIdx.z * outB;
  int c0 = blockIdx.x * 32, r0 = blockIdx.y * 32;
  int x = threadIdx.x, y = threadIdx.y; // (32,8)
#pragma unroll
  for (int yy = 0; yy < 32; yy += 8)
    tile[y + yy][x] = inp[(long)(r0 + y + yy) * C + c0 + x];
  __syncthreads();
#pragma unroll
  for (int yy = 0; yy < 32; yy += 8)
    outp[(long)(c0 + y + yy) * R + r0 + x] = f2bf(tile[x][y + yy]);
}

// ---------------- rmsnorm rows (f32 in, bf16 out) ----------------
__global__ void rmsnorm_rows(const float* __restrict__ in, const float* __restrict__ w,
                             unsigned short* __restrict__ out, int C) {
  int t = blockIdx.x, tid = threadIdx.x;
  __shared__ float sred[4];
  const float* row = in + (long)t * C;
  float ss = 0.f;
  for (int i = tid; i < C; i += 256) { float v = row[i]; ss += v * v; }
#pragma unroll
  for (int o = 32; o; o >>= 1) ss += __shfl_xor(ss, o);
  if ((tid & 63) == 0) sred[tid >> 6] = ss;
  __syncthreads();
  ss = sred[0] + sred[1] + sred[2] + sred[3];
  float rinv = rsqrtf(ss / (float)C + EPS_F);
  for (int i = tid; i < C; i += 256)
    out[(long)t * C + i] = f2bf(row[i] * rinv * w[i]);
}

// ---------------- kv latent: rmsnorm(512)->k_input & v_t; rope on k_pe ----------------
__global__ void norm_rope_k(const float* __restrict__ latent, const float* __restrict__ w,
                            unsigned short* __restrict__ k_input, unsigned short* __restrict__ v_t) {
  int t = blockIdx.x, tid = threadIdx.x;
  __shared__ float sred[4];
  const float* row = latent + (long)t * 576;
  float ss = 0.f;
  for (int i = tid; i < 512; i += 256) { float v = row[i]; ss += v * v; }
#pragma unroll
  for (int o = 32; o; o >>= 1) ss += __shfl_xor(ss, o);
  if ((tid & 63) == 0) sred[tid >> 6] = ss;
  __syncthreads();
  ss = sred[0] + sred[1] + sred[2] + sred[3];
  float rinv = rsqrtf(ss * (1.f / 512.f) + EPS_F);
  for (int i = tid; i < 512; i += 256) {
    unsigned short b = f2bf(row[i] * rinv * w[i]);
    k_input[(long)t * 576 + i] = b;
    v_t[(long)i * T_SEQ + t] = b;  // V^T for PV MFMA B-frags
  }
  if (tid < 32) {
    float fr = (float)t * expf(-((float)(2 * tid) / 64.f) * LN10000);
    float c = cosf(fr), s = sinf(fr);
    float x1 = row[512 + 2 * tid], x2 = row[512 + 2 * tid + 1];
    k_input[(long)t * 576 + 512 + 2 * tid]     = f2bf(x1 * c - x2 * s);
    k_input[(long)t * 576 + 512 + 2 * tid + 1] = f2bf(x2 * c + x1 * s);
  }
}

// ---------------- rope on q_pe: q (T, H*192) -> q_input[h][t][512..576] ----------------
__global__ void rope_q(const unsigned short* __restrict__ q, unsigned short* __restrict__ q_input) {
  int idx = blockIdx.x * 256 + threadIdx.x; // t*NH*32 + h*32 + i
  int i = idx & 31, h = (idx >> 5) & 31, t = idx >> 10;
  float fr = (float)t * expf(-((float)(2 * i) / 64.f) * LN10000);
  float c = cosf(fr), s = sinf(fr);
  const unsigned short* qp = q + (long)t * (NH * QKD) + h * QKD + NOPE + 2 * i;
  float x1 = bf2f(qp[0]), x2 = bf2f(qp[1]);
  unsigned short* op = q_input + ((long)h * T_SEQ + t) * 576 + 512 + 2 * i;
  op[0] = f2bf(x1 * c - x2 * s);
  op[1] = f2bf(x2 * c + x1 * s);
}

// ---------------- GEMM: C[M,N] = A[M,K] @ Bt[N,K]^T (bf16 in, f32 acc) ----------------
template <bool OUT_BF16>
__global__ __launch_bounds__(256, 2)
void gemm_bt(const unsigned short* __restrict__ A, const unsigned short* __restrict__ Bt,
             void* __restrict__ Cv, int N, int K,
             long lda, long ldb, long ldc, long bA, long bB, long bC) {
  __shared__ __align__(16) unsigned short sA[128 * 64];
  __shared__ __align__(16) unsigned short sB[128 * 64];
  const int b = blockIdx.z;
  const unsigned short* Ap = A + (long)b * bA;
  const unsigned short* Bp = Bt + (long)b * bB;
  const int m0 = blockIdx.x * 128, n0 = blockIdx.y * 128;
  const int tid = threadIdx.x, lane = tid & 63, w = tid >> 6;
  const int wr = w >> 1, wc = w & 1, lo = lane & 15, hi = lane >> 4;
  f32x4 acc[4][4];
#pragma unroll
  for (int i = 0; i < 4; i++)
#pragma unroll
    for (int j = 0; j < 4; j++) acc[i][j] = (f32x4){0.f, 0.f, 0.f, 0.f};
  const int r0 = tid >> 3, cc = tid & 7;
  for (int k0 = 0; k0 < K; k0 += 64) {
    __syncthreads();
#pragma unroll
    for (int i = 0; i < 4; i++) {
      glds16(Ap + (long)(m0 + i * 32 + r0) * lda + k0 + cc * 8, sA + i * 2048 + w * 512);
      glds16(Bp + (long)(n0 + i * 32 + r0) * ldb + k0 + cc * 8, sB + i * 2048 + w * 512);
    }
    __syncthreads();
#pragma unroll
    for (int s = 0; s < 2; s++) {
      bf16x8 af[4], bfr[4];
#pragma unroll
      for (int mt = 0; mt < 4; mt++)
        af[mt] = *(const bf16x8*)(sA + (wr * 64 + mt * 16 + lo) * 64 + s * 32 + hi * 8);
#pragma unroll
      for (int nt = 0; nt < 4; nt++)
        bfr[nt] = *(const bf16x8*)(sB + (wc * 64 + nt * 16 + lo) * 64 + s * 32 + hi * 8);
#pragma unroll
      for (int mt = 0; mt < 4; mt++)
#pragma unroll
        for (int nt = 0; nt < 4; nt++)
          acc[mt][nt] = __builtin_amdgcn_mfma_f32_16x16x32_bf16(af[mt], bfr[nt], acc[mt][nt], 0, 0, 0);
    }
  }
#pragma unroll
  for (int mt = 0; mt < 4; mt++)
#pragma unroll
    for (int nt = 0; nt < 4; nt++) {
      int col = n0 + wc * 64 + nt * 16 + lo;
      if (col < N) {
#pragma unroll
        for (int r = 0; r < 4; r++) {
          long row = m0 + wr * 64 + mt * 16 + hi * 4 + r;
          float v = acc[mt][nt][r];
          if constexpr (OUT_BF16)
            ((unsigned short*)Cv)[(long)b * bC + row * ldc + col] = f2bf(v);
          else
            ((float*)Cv)[(long)b * bC + row * ldc + col] = v;
        }
      }
    }
}

// ---------------- flash attention v4: S^T trick + no-max softmax + glds16 slots ----------------
// grid (NH, 32) i-reversed. 4 waves x 16 Q-rows. Per j-tile (64 keys): 10 slots
// (6 K-chunks of 96 dims + 4 V-chunks of 128 vd), one barrier per slot, glds16
// prefetch of slot s+1 issued right after slot-s barrier (m97 pattern).
// S^T = mfma(A=K-frag, B=Q-frag) puts per-row stats in regs (2 shuffles total);
// P converts to PV A-frags in-register via bpermute. No sP, no of-rescale.
__global__ __launch_bounds__(256, 2)
void flash_attn(const unsigned short* __restrict__ q_input,
                const unsigned short* __restrict__ k_input,
                const unsigned short* __restrict__ v_t,
                unsigned short* __restrict__ ctx_out) {
  __shared__ __align__(16) unsigned short sK[2 * 64 * 96];   // 24 KB
  __shared__ __align__(16) unsigned short sV[2 * 128 * 64];  // 32 KB
  const int h = blockIdx.x;
  const int i0 = (31 - blockIdx.y) * 64;  // biggest blocks dispatch first
  const int tid = threadIdx.x;
  const int lane = tid & 63, w = tid >> 6;
  const int lo = lane & 15, hi = lane >> 4;
  const int qrow = i0 + w * 16 + lo;

  bf16x8 qf[18];
  {
    const unsigned short* qr = q_input + ((long)h * T_SEQ + qrow) * 576;
#pragma unroll
    for (int i = 0; i < 18; i++) qf[i] = *(const bf16x8*)(qr + i * 32 + hi * 8);
  }
  float l_r = 0.f;
  f32x4 of[32];
#pragma unroll
  for (int o = 0; o < 32; o++) of[o] = (f32x4){0.f, 0.f, 0.f, 0.f};

  // staging lane constants (32-bit element offsets from k_input / v_t)
  int kOff[3];
#pragma unroll
  for (int i = 0; i < 3; i++) {
    int u = w * 192 + i * 64 + lane;
    int key = (u * 683) >> 13;          // u / 12
    int dg = u - 12 * key;
    kOff[i] = key * 576 + dg * 8;
  }
  int vOff[4];
#pragma unroll
  for (int i = 0; i < 4; i++) {
    int u = w * 256 + i * 64 + lane;
    vOff[i] = (u >> 3) * T_SEQ + (u & 7) * 8;
  }
  unsigned short* kdst = sK + w * 3 * 512;  // + i*512 + buf*6144
  unsigned short* vdst = sV + w * 4 * 512;  // + i*512 + buf*8192
  const unsigned short* kld = sK + lo * 96 + hi * 8;   // + buf*6144 + nt*1536 + ks*32
  const unsigned short* vld = sV + lo * 64 + hi * 8;   // + buf*8192 + ot*1024 + kk*32

  // prologue: K chunk 0 of first j-tile -> sK[buf0]
#pragma unroll
  for (int i = 0; i < 3; i++) glds16(k_input + kOff[i], kdst + i * 512);

  for (int j0 = 0; j0 <= i0; j0 += 64) {
    f32x4 sacc[4];
#pragma unroll
    for (int nt = 0; nt < 4; nt++) sacc[nt] = (f32x4){0.f, 0.f, 0.f, 0.f};
    // ---- K slots: S^T accumulation ----
#pragma unroll
    for (int c = 0; c < 6; c++) {
      __syncthreads();
      if (c < 5) {
        const int bn = (c + 1) & 1;
#pragma unroll
        for (int i = 0; i < 3; i++)
          glds16(k_input + kOff[i] + (c + 1) * 96, kdst + bn * 6144 + i * 512);
      } else {
#pragma unroll
        for (int i = 0; i < 4; i++) glds16(v_t + vOff[i], vdst + i * 512);
      }
      const unsigned short* kb = kld + (c & 1) * 6144;
#pragma unroll
      for (int ks = 0; ks < 3; ks++)
#pragma unroll
        for (int nt = 0; nt < 4; nt++) {
          bf16x8 a = *(const bf16x8*)(kb + nt * 1536 + ks * 32);
          sacc[nt] = __builtin_amdgcn_mfma_f32_16x16x32_bf16(a, qf[3 * c + ks], sacc[nt], 0, 0, 0);
        }
    }
    // ---- softmax (no max-tracking; stats are per-lane) ----
    const bool diag = (j0 == i0);
    int D2[4][2];
    float psum = 0.f;
#pragma unroll
    for (int nt = 0; nt < 4; nt++) {
      float pv[4];
#pragma unroll
      for (int r = 0; r < 4; r++) {
        float e = __expf(sacc[nt][r] * SCALE);
        if (diag && (j0 + nt * 16 + hi * 4 + r) > qrow) e = 0.f;
        pv[r] = e;
        psum += e;
      }
      D2[nt][0] = (int)f2bf(pv[0]) | ((int)f2bf(pv[1]) << 16);
      D2[nt][1] = (int)f2bf(pv[2]) | ((int)f2bf(pv[3]) << 16);
    }
    psum += __shfl_xor(psum, 16);
    psum += __shfl_xor(psum, 32);
    l_r += psum;
    // ---- P -> PV A-frags in-register (two bpermute rounds + select) ----
    bf16x8 pa[2];
    {
      const int s0 = lo + 32 * (hi & 1);
#pragma unroll
      for (int kk = 0; kk < 2; kk++) {
        int d[4];
#pragma unroll
        for (int dd = 0; dd < 2; dd++) {
          int t0 = __shfl(D2[2 * kk][dd], s0);
          int t1 = __shfl(D2[2 * kk + 1][dd], s0);
          d[dd] = (hi >> 1) ? t1 : t0;
          int t2 = __shfl(D2[2 * kk][dd], s0 + 16);
          int t3 = __shfl(D2[2 * kk + 1][dd], s0 + 16);
          d[2 + dd] = (hi >> 1) ? t3 : t2;
        }
        int4 di = {d[0], d[1], d[2], d[3]};
        pa[kk] = *(bf16x8*)&di;
      }
    }
    // ---- V slots: O += P V ----
#pragma unroll
    for (int ch = 0; ch < 4; ch++) {
      __syncthreads();
      if (ch < 3) {
        const int bn = (ch + 1) & 1;
#pragma unroll
        for (int i = 0; i < 4; i++)
          glds16(v_t + vOff[i] + (ch + 1) * 128 * T_SEQ, vdst + bn * 8192 + i * 512);
      } else {
#pragma unroll
        for (int i = 0; i < 3; i++) kOff[i] += 64 * 576;
#pragma unroll
        for (int i = 0; i < 4; i++) vOff[i] += 64;
        if (j0 < i0) {
#pragma unroll
          for (int i = 0; i < 3; i++) glds16(k_input + kOff[i], kdst + i * 512);
        }
      }
      const unsigned short* vb = vld + (ch & 1) * 8192;
#pragma unroll
      for (int kk = 0; kk < 2; kk++)
#pragma unroll
        for (int ot = 0; ot < 8; ot++) {
          bf16x8 bfr = *(const bf16x8*)(vb + ot * 1024 + kk * 32);
          of[ch * 8 + ot] =
              __builtin_amdgcn_mfma_f32_16x16x32_bf16(pa[kk], bfr, of[ch * 8 + ot], 0, 0, 0);
        }
    }
  }
  // ---- epilogue ----
  float linv[4];
#pragma unroll
  for (int r = 0; r < 4; r++) linv[r] = 1.f / __shfl(l_r, hi * 4 + r);
#pragma unroll
  for (int o = 0; o < 32; o++) {
    int vd = (o >> 3) * 128 + (o & 7) * 16 + lo;
#pragma unroll
    for (int r = 0; r < 4; r++) {
      long row = (long)h * T_SEQ + i0 + w * 16 + hi * 4 + r;
      ctx_out[row * 576 + vd] = f2bf(of[o][r] * linv[r]);
    }
  }
}

// ---------------- host orchestration ----------------
extern "C" void kernel_launch(void* const* d_in, const int* in_sizes, int n_in,
                              void* d_out, int out_size, void* d_ws, size_t ws_size,
                              hipStream_t stream) {
  (void)in_sizes; (void)n_in; (void)out_size; (void)ws_size;
  const float* hs    = (const float*)d_in[0];
  const float* wqa   = (const float*)d_in[2];
  const float* qlnw  = (const float*)d_in[3];
  const float* wqb   = (const float*)d_in[4];
  const float* wkva  = (const float*)d_in[5];
  const float* kvlnw = (const float*)d_in[6];
  const float* wkc   = (const float*)d_in[7];
  const float* wvc   = (const float*)d_in[8];
  const float* wo    = (const float*)d_in[9];
  float* out = (float*)d_out;

  char* base = (char*)d_ws;
  size_t off = 0;
  auto alloc = [&](size_t bytes) {
    char* r = base + off;
    off += (bytes + 255) & ~(size_t)255;
    return r;
  };
  unsigned short* hs_b  = (unsigned short*)alloc((size_t)T_SEQ * HID * 2);
  unsigned short* wqaT  = (unsigned short*)alloc((size_t)QLR * HID * 2);
  unsigned short* wqbT  = (unsigned short*)alloc((size_t)NH * QKD * QLR * 2);
  unsigned short* wkvaT = (unsigned short*)alloc((size_t)640 * HID * 2);  // 576 padded to 640
  unsigned short* wkcT  = (unsigned short*)alloc((size_t)NH * 512 * 128 * 2);
  unsigned short* wvcT  = (unsigned short*)alloc((size_t)NH * 128 * 512 * 2);
  float*          q_a   = (float*)alloc((size_t)T_SEQ * QLR * 4);
  unsigned short* q_a_n = (unsigned short*)alloc((size_t)T_SEQ * QLR * 2);
  unsigned short* qbuf  = (unsigned short*)alloc((size_t)T_SEQ * NH * QKD * 2);
  float*          latent= (float*)alloc((size_t)T_SEQ * 576 * 4);
  unsigned short* k_inp = (unsigned short*)alloc((size_t)T_SEQ * 576 * 2);
  unsigned short* v_t   = (unsigned short*)alloc((size_t)512 * T_SEQ * 2);
  unsigned short* q_inp = (unsigned short*)alloc((size_t)NH * T_SEQ * 576 * 2);
  unsigned short* woT   = (unsigned short*)base;  // over hs_b+wqaT+wqbT (dead by then)
  unsigned short* attn  = qbuf;                   // over qbuf (dead by then)

  dim3 tb(32, 8);
  conv_f2b<<<(T_SEQ * HID) / 1024, 256, 0, stream>>>(hs, hs_b, (long)T_SEQ * HID);
  transpose_f2b<<<dim3(QLR / 32, HID / 32, 1), tb, 0, stream>>>(wqa, wqaT, HID, QLR, 0, 0);
  transpose_f2b<<<dim3(576 / 32, HID / 32, 1), tb, 0, stream>>>(wkva, wkvaT, HID, 576, 0, 0);
  gemm_bt<false><<<dim3(T_SEQ / 128, QLR / 128, 1), 256, 0, stream>>>(
      hs_b, wqaT, q_a, QLR, HID, HID, HID, QLR, 0, 0, 0);
  gemm_bt<false><<<dim3(T_SEQ / 128, 5, 1), 256, 0, stream>>>(
      hs_b, wkvaT, latent, 576, HID, HID, HID, 576, 0, 0, 0);
  rmsnorm_rows<<<T_SEQ, 256, 0, stream>>>(q_a, qlnw, q_a_n, QLR);
  norm_rope_k<<<T_SEQ, 256, 0, stream>>>(latent, kvlnw, k_inp, v_t);
  transpose_f2b<<<dim3((NH * QKD) / 32, QLR / 32, 1), tb, 0, stream>>>(wqb, wqbT, QLR, NH * QKD, 0, 0);
  gemm_bt<true><<<dim3(T_SEQ / 128, (NH * QKD) / 128, 1), 256, 0, stream>>>(
      q_a_n, wqbT, qbuf, NH * QKD, QLR, QLR, QLR, NH * QKD, 0, 0, 0);
  transpose_f2b<<<dim3(512 / 32, 128 / 32, NH), tb, 0, stream>>>(wkc, wkcT, 128, 512, 65536, 65536);
  gemm_bt<true><<<dim3(T_SEQ / 128, 512 / 128, NH), 256, 0, stream>>>(
      qbuf, wkcT, q_inp, 512, 128, NH * QKD, 128, 576, QKD, 65536, (long)T_SEQ * 576);
  rope_q<<<(T_SEQ * NH * 32) / 256, 256, 0, stream>>>(qbuf, q_inp);
  flash_attn<<<dim3(NH, 32), 256, 0, stream>>>(q_inp, k_inp, v_t, q_inp);
  transpose_f2b<<<dim3(128 / 32, 512 / 32, NH), tb, 0, stream>>>(wvc, wvcT, 512, 128, 65536, 65536);
  gemm_bt<true><<<dim3(T_SEQ / 128, 1, NH), 256, 0, stream>>>(
      q_inp, wvcT, attn, 128, 512, 576, 512, NH * VDIM, (long)T_SEQ * 576, 65536, 128);
  transpose_f2b<<<dim3(HID / 32, (NH * VDIM) / 32, 1), tb, 0, stream>>>(wo, woT, NH * VDIM, HID, 0, 0);
  gemm_bt<false><<<dim3(T_SEQ / 128, HID / 128, 1), 256, 0, stream>>>(
      attn, woT, out, HID, NH * VDIM, NH * VDIM, NH * VDIM, HID, 0, 0, 0);
}